// Round 14
// baseline (136.437 us; speedup 1.0000x reference)
//
#include <hip/hip_runtime.h>

// ---------------------------------------------------------------------------
// MaskAttentionHead v14: more chains/CU, shorter tails.
//  pack_w: W -> bf16 fragment-linear WF (1/8 folded into Wq)
//  qkv:    1024 blocks x 16 rows (4 blocks/CU -> 4 interleaved DMA pipelines);
//          K in 8 steps of 128; x staged via row-major global_load_lds with
//          in-line XOR bank swizzle; W direct from L2; 4 waves split N.
//  flash:  512 blocks x 512 threads; 8 waves = 8-way si-split (tail <= 9
//          iters, 4 waves/SIMD); BM=32/wave; 2-phase in-LDS combine.
// ws: WF 384KB | Qg 2MB | KF 2MB | VF 2MB  (~6.7MB)
// ---------------------------------------------------------------------------

typedef __attribute__((ext_vector_type(8))) short v8s;   // 8 x bf16
typedef __attribute__((ext_vector_type(4))) float v4f;   // MFMA 16x16 C/D

static __device__ __forceinline__ unsigned short f2bf(float x) {
  unsigned int u = __builtin_bit_cast(unsigned int, x);
  u += 0x7fffu + ((u >> 16) & 1u);          // RNE
  return (unsigned short)(u >> 16);
}

// async 16B/lane global->LDS DMA: dst wave-uniform base, lane i -> dst+i*16.
static __device__ __forceinline__ void dma16(const void* src, void* dst) {
  __builtin_amdgcn_global_load_lds(
      (const __attribute__((address_space(1))) void*)src,
      (__attribute__((address_space(3))) void*)dst, 16, 0, 0);
}

// --- kernel 1: pack weights into WF ----------------------------------------
__global__ __launch_bounds__(256) void pack_w(const float* __restrict__ Wq,
                                              const float* __restrict__ Wk,
                                              const float* __restrict__ Wv,
                                              unsigned short* __restrict__ WF) {
  int idx = (blockIdx.x * 256 + threadIdx.x) * 4;  // 192*1024 total
  int row = idx >> 10;
  int k   = idx & 1023;
  const float* src;
  float scale;
  if (row < 64)       { src = Wq + row * 1024 + k;         scale = 0.125f; }
  else if (row < 128) { src = Wk + (row - 64) * 1024 + k;  scale = 1.0f;   }
  else                { src = Wv + (row - 128) * 1024 + k; scale = 1.0f;   }
  float4 f = *(const float4*)src;
  ushort4 o;
  o.x = f2bf(f.x * scale); o.y = f2bf(f.y * scale);
  o.z = f2bf(f.z * scale); o.w = f2bf(f.w * scale);
  size_t off = ((size_t)(k >> 5) * 12 + (row >> 4)) * 512 +
               (((k >> 3) & 3) * 16 + (row & 15)) * 8 + (k & 7);
  *(ushort4*)(WF + off) = o;
}

// --- kernel 2: QKV projection, 16 rows/block, 4 blocks/CU -------------------
// 1024 blocks x 256 threads. K in 8 steps of 128. x-stage 8 KB/step: chunk
// j in [0,8) = rows {2j,2j+1} x 512B contiguous; wave wv stages j in
// {2wv, 2wv+1}. LDS unit (r,su) holds global unit u = su ^ (r&7).
// Compute: wave wv does n-tiles {wv*3..wv*3+2} for the single 16-row m-group.
__global__ __launch_bounds__(256) void qkv(const float* __restrict__ x,
                                           const unsigned short* __restrict__ WF,
                                           unsigned short* __restrict__ Qg,
                                           unsigned short* __restrict__ KF,
                                           unsigned short* __restrict__ VF) {
  __shared__ alignas(16) char xs[2][8192];
  const int tid   = threadIdx.x;
  const int lane  = tid & 63;
  const int wv    = tid >> 6;        // 0..3
  const int quad  = lane >> 4;
  const int colid = lane & 15;
  const int row0  = blockIdx.x * 16;

  const char* xB = (const char*)x;
  const unsigned short* wf = WF + lane * 8;

  const int rpar = lane >> 5;          // which of the chunk's two rows
  const int su_l = lane & 31;          // stored unit
  const int c7   = colid & 7;

  v4f acc[3];
#pragma unroll
  for (int i = 0; i < 3; i++) acc[i] = (v4f){0.f, 0.f, 0.f, 0.f};

  auto stage = [&](int kt, int slot) {
#pragma unroll
    for (int i = 0; i < 2; i++) {
      int j    = wv * 2 + i;           // chunk = rows {2j, 2j+1}
      int rloc = 2 * j + rpar;
      int u    = su_l ^ (rloc & 7);    // in-line XOR swizzle
      const char* src = xB + (size_t)(row0 + rloc) * 4096 + kt * 512 + u * 16;
      dma16(src, &xs[slot][j * 1024]);
    }
  };

  stage(0, 0);

  for (int kt = 0; kt < 8; kt++) {
    const int slot = kt & 1;
    __syncthreads();                       // drain stage kt
    if (kt < 7) stage(kt + 1, slot ^ 1);   // overlaps compute kt
#pragma unroll
    for (int s = 0; s < 4; s++) {
      const int g = kt * 4 + s;
      v8s bw[3];
#pragma unroll
      for (int ntl = 0; ntl < 3; ntl++)
        bw[ntl] = *(const v8s*)(wf + ((size_t)g * 12 + wv * 3 + ntl) * 512);
      const int u0 = s * 8 + quad * 2;
      float4 f0 = *(const float4*)(&xs[slot][colid * 512 + (u0 ^ c7) * 16]);
      float4 f1 = *(const float4*)(&xs[slot][colid * 512 + ((u0 + 1) ^ c7) * 16]);
      v8s a;
      a[0] = (short)f2bf(f0.x); a[1] = (short)f2bf(f0.y);
      a[2] = (short)f2bf(f0.z); a[3] = (short)f2bf(f0.w);
      a[4] = (short)f2bf(f1.x); a[5] = (short)f2bf(f1.y);
      a[6] = (short)f2bf(f1.z); a[7] = (short)f2bf(f1.w);
#pragma unroll
      for (int ntl = 0; ntl < 3; ntl++)
        acc[ntl] = __builtin_amdgcn_mfma_f32_16x16x32_bf16(a, bw[ntl], acc[ntl], 0, 0, 0);
    }
  }

  // epilogue: wave wv stores n-tiles wv*3..wv*3+2
  const int trow_base = row0 + quad * 4;   // C/D row = quad*4+r, col = colid
#pragma unroll
  for (int ntl = 0; ntl < 3; ntl++) {
    const int nt = wv * 3 + ntl;
    if (nt < 4) {
#pragma unroll
      for (int r = 0; r < 4; r++)
        Qg[(size_t)(trow_base + r) * 64 + nt * 16 + colid] = f2bf(acc[ntl][r]);
    } else if (nt < 8) {
      int half = (nt - 4) >> 1;
      int q_f  = ((nt - 4) * 2 + (colid >> 3)) & 3;
      int j    = colid & 7;
#pragma unroll
      for (int r = 0; r < 4; r++) {
        int t  = trow_base + r;
        int b  = t >> 12, tl = t & 4095;
        int si = tl >> 6, sl = tl & 63;
        KF[((size_t)(b * 64 + si) * 8 + (sl >> 4) * 2 + half) * 512 +
           (q_f * 16 + (sl & 15)) * 8 + j] = f2bf(acc[ntl][r]);
      }
    } else {
#pragma unroll
      for (int r = 0; r < 4; r++) {
        int t  = trow_base + r;
        int b  = t >> 12, tl = t & 4095;
        int si = tl >> 6;
        int half = (tl >> 5) & 1, q_f = (tl >> 3) & 3, j = tl & 7;
        VF[((size_t)(b * 64 + si) * 8 + (nt - 8) * 2 + half) * 512 +
           (q_f * 16 + colid) * 8 + j] = f2bf(acc[ntl][r]);
      }
    }
  }
}

// --- kernel 3: causal flash, 8 waves = 8-way si-split -----------------------
// 512 blocks x 512 threads: qt32 = 127 - bid>>2 (longest-first), b = bid&3.
// Loop phase: pl[8 waves][2 mt][16*72] shorts (36864 B).
// Reduce phase: 4 slots redf[4][32][68] + lred[4][32] (35328 B), 2-phase tree.
__global__ __launch_bounds__(512) void flash(const unsigned short* __restrict__ Qg,
                                             const unsigned short* __restrict__ KF,
                                             const unsigned short* __restrict__ VF,
                                             float* __restrict__ out) {
  __shared__ alignas(16) char smem[8 * 2 * 16 * 72 * 2];   // 36864 B
  unsigned short* pl = (unsigned short*)smem;
  float* redf = (float*)smem;                              // 4*32*68 floats
  float* lred = (float*)(smem + 4 * 32 * 68 * 4);          // 4*32 floats

  const int tid   = threadIdx.x;
  const int lane  = tid & 63;
  const int wv    = tid >> 6;               // si-split id 0..7
  const int quad  = lane >> 4;
  const int colid = lane & 15;
  const int qt32  = 127 - (int)(blockIdx.x >> 2);   // longest-first
  const int b     = blockIdx.x & 3;
  const int bT    = b * 4096;
  const int row00 = qt32 * 32;
  const int qimax = (row00 + 31) >> 6;

  v8s qf[2][2];
#pragma unroll
  for (int mt = 0; mt < 2; mt++) {
    const unsigned short* qrow =
        Qg + (size_t)(bT + row00 + mt * 16 + colid) * 64 + quad * 8;
    qf[mt][0] = *(const v8s*)(qrow);
    qf[mt][1] = *(const v8s*)(qrow + 32);
  }

  v8s ones;
#pragma unroll
  for (int j = 0; j < 8; j++) ones[j] = (short)0x3F80;  // bf16 1.0

  v4f o[2][4];
#pragma unroll
  for (int mt = 0; mt < 2; mt++)
#pragma unroll
    for (int i = 0; i < 4; i++) o[mt][i] = (v4f){0.f, 0.f, 0.f, 0.f};
  v4f lac[2];
  lac[0] = (v4f){0.f, 0.f, 0.f, 0.f};
  lac[1] = (v4f){0.f, 0.f, 0.f, 0.f};

  const unsigned short* kb0 = KF + (size_t)b * 64 * 4096 + lane * 8;
  const unsigned short* vb0 = VF + (size_t)b * 64 * 4096 + lane * 8;

  for (int si = wv; si <= qimax; si += 8) {
    const unsigned short* ktile = kb0 + (size_t)si * 4096;
    const unsigned short* vtile = vb0 + (size_t)si * 4096;
    v8s ck[8], cv[8];
#pragma unroll
    for (int c = 0; c < 8; c++) ck[c] = *(const v8s*)(ktile + (size_t)c * 512);
#pragma unroll
    for (int c = 0; c < 8; c++) cv[c] = *(const v8s*)(vtile + (size_t)c * 512);

#pragma unroll
    for (int mt = 0; mt < 2; mt++) {
      v4f s[4];
#pragma unroll
      for (int i = 0; i < 4; i++) s[i] = (v4f){0.f, 0.f, 0.f, 0.f};
#pragma unroll
      for (int nt = 0; nt < 4; nt++) {
        s[nt] = __builtin_amdgcn_mfma_f32_16x16x32_bf16(qf[mt][0], ck[2 * nt], s[nt], 0, 0, 0);
        s[nt] = __builtin_amdgcn_mfma_f32_16x16x32_bf16(qf[mt][1], ck[2 * nt + 1], s[nt], 0, 0, 0);
      }

      if (si == qimax) {    // diagonal-containing tile: causal mask
        int rowb = row00 + mt * 16 + quad * 4;
        int colb = si * 64;
#pragma unroll
        for (int nt = 0; nt < 4; nt++)
#pragma unroll
          for (int r = 0; r < 4; r++)
            if (colb + nt * 16 + colid > rowb + r) s[nt][r] = -1e30f;
      }

      unsigned short* pw = pl + (wv * 2 + mt) * (16 * 72);
#pragma unroll
      for (int nt = 0; nt < 4; nt++)
#pragma unroll
        for (int r = 0; r < 4; r++)
          pw[(quad * 4 + r) * 72 + nt * 16 + colid] = f2bf(__expf(s[nt][r]));
    }

#pragma unroll
    for (int mt = 0; mt < 2; mt++) {
      unsigned short* pw = pl + (wv * 2 + mt) * (16 * 72);
#pragma unroll
      for (int ks = 0; ks < 64; ks += 32) {
        v8s af = *(const v8s*)(&pw[colid * 72 + ks + quad * 8]);
        lac[mt] = __builtin_amdgcn_mfma_f32_16x16x32_bf16(af, ones, lac[mt], 0, 0, 0);
#pragma unroll
        for (int nt = 0; nt < 4; nt++)
          o[mt][nt] = __builtin_amdgcn_mfma_f32_16x16x32_bf16(
              af, cv[2 * nt + (ks >> 5)], o[mt][nt], 0, 0, 0);
      }
    }
  }

  // ---- 2-phase cross-wave combine (4 LDS slots) ----
  __syncthreads();                 // done with pl
  if (wv >= 4) {                   // phase 1: waves 4..7 -> slots 0..3
    int slot = wv - 4;
#pragma unroll
    for (int mt = 0; mt < 2; mt++) {
#pragma unroll
      for (int nt = 0; nt < 4; nt++)
#pragma unroll
        for (int r = 0; r < 4; r++)
          redf[(slot * 32 + mt * 16 + quad * 4 + r) * 68 + nt * 16 + colid] = o[mt][nt][r];
      if (colid == 0) {
#pragma unroll
        for (int r = 0; r < 4; r++)
          lred[slot * 32 + mt * 16 + quad * 4 + r] = lac[mt][r];
      }
    }
  }
  __syncthreads();
  if (wv < 4) {                    // waves 0..3 absorb slots 0..3
#pragma unroll
    for (int mt = 0; mt < 2; mt++) {
#pragma unroll
      for (int nt = 0; nt < 4; nt++)
#pragma unroll
        for (int r = 0; r < 4; r++)
          o[mt][nt][r] += redf[(wv * 32 + mt * 16 + quad * 4 + r) * 68 + nt * 16 + colid];
#pragma unroll
      for (int r = 0; r < 4; r++)
        lac[mt][r] += lred[wv * 32 + mt * 16 + quad * 4 + r];
    }
  }
  __syncthreads();
  if (wv >= 1 && wv < 4) {         // phase 2: waves 1..3 -> slots 0..2
    int slot = wv - 1;
#pragma unroll
    for (int mt = 0; mt < 2; mt++) {
#pragma unroll
      for (int nt = 0; nt < 4; nt++)
#pragma unroll
        for (int r = 0; r < 4; r++)
          redf[(slot * 32 + mt * 16 + quad * 4 + r) * 68 + nt * 16 + colid] = o[mt][nt][r];
      if (colid == 0) {
#pragma unroll
        for (int r = 0; r < 4; r++)
          lred[slot * 32 + mt * 16 + quad * 4 + r] = lac[mt][r];
      }
    }
  }
  __syncthreads();
  if (wv == 0) {                   // wave 0: final sum + store
#pragma unroll
    for (int mt = 0; mt < 2; mt++)
#pragma unroll
      for (int r = 0; r < 4; r++) {
        int row = mt * 16 + quad * 4 + r;
        float lsum = lac[mt][r] + lred[row] + lred[32 + row] + lred[64 + row];
        float inv = 1.0f / lsum;
#pragma unroll
        for (int nt = 0; nt < 4; nt++) {
          float sum = o[mt][nt][r] + redf[row * 68 + nt * 16 + colid] +
                      redf[(32 + row) * 68 + nt * 16 + colid] +
                      redf[(64 + row) * 68 + nt * 16 + colid];
          out[(size_t)(bT + row00 + row) * 64 + nt * 16 + colid] = sum * inv;
        }
      }
  }
}

extern "C" void kernel_launch(void* const* d_in, const int* in_sizes, int n_in,
                              void* d_out, int out_size, void* d_ws, size_t ws_size,
                              hipStream_t stream) {
  const float* x  = (const float*)d_in[0];
  const float* Wq = (const float*)d_in[1];
  const float* Wk = (const float*)d_in[2];
  const float* Wv = (const float*)d_in[3];
  float* out = (float*)d_out;

  unsigned short* WF = (unsigned short*)d_ws;          // 192*1024
  unsigned short* Qg = WF + 192 * 1024;                // 16384*64 row-major
  unsigned short* KF = Qg + 16384 * 64;                // fragment-linear
  unsigned short* VF = KF + 16384 * 64;                // fragment-linear

  hipLaunchKernelGGL(pack_w, dim3(192), dim3(256), 0, stream, Wq, Wk, Wv, WF);
  hipLaunchKernelGGL(qkv, dim3(1024), dim3(256), 0, stream, x, WF, Qg, KF, VF);
  hipLaunchKernelGGL(flash, dim3(512), dim3(512), 0, stream, Qg, KF, VF, out);
}

// Round 15
// 132.491 us; speedup vs baseline: 1.0298x; 1.0298x over previous
//
#include <hip/hip_runtime.h>

// ---------------------------------------------------------------------------
// MaskAttentionHead v15: qkv = one contiguous 64KB mega-DMA per block.
//  pack_w: W -> bf16 fragment-linear WF (1/8 folded into Wq)
//  qkv:    1024 blocks x 16 rows (2 blocks/CU, LDS 64KB each); whole x-slab
//          (16 rows x 4KB, CONTIGUOUS in HBM) staged via global_load_lds with
//          in-line XOR row swizzle; one barrier; K=1024 computed from LDS,
//          W fragments direct from L2; 4 waves split N (3 n-tiles each).
//  flash:  R13 version verbatim (512 blocks, BM=32/wave, 4-way si-split,
//          barrier-free loop, in-LDS combine) - best measured so far.
// ws: WF 384KB | Qg 2MB | KF 2MB | VF 2MB  (~6.7MB)
// ---------------------------------------------------------------------------

typedef __attribute__((ext_vector_type(8))) short v8s;   // 8 x bf16
typedef __attribute__((ext_vector_type(4))) float v4f;   // MFMA 16x16 C/D

static __device__ __forceinline__ unsigned short f2bf(float x) {
  unsigned int u = __builtin_bit_cast(unsigned int, x);
  u += 0x7fffu + ((u >> 16) & 1u);          // RNE
  return (unsigned short)(u >> 16);
}

// async 16B/lane global->LDS DMA: dst wave-uniform base, lane i -> dst+i*16.
static __device__ __forceinline__ void dma16(const void* src, void* dst) {
  __builtin_amdgcn_global_load_lds(
      (const __attribute__((address_space(1))) void*)src,
      (__attribute__((address_space(3))) void*)dst, 16, 0, 0);
}

// --- kernel 1: pack weights into WF ----------------------------------------
// WF chunk (g*12+nt)*512 (+lane*8) = B-fragment for 32-K group g, n-tile nt:
// lane(quad,colid) holds W[n=nt*16+colid][k=g*32+quad*8+j].
__global__ __launch_bounds__(256) void pack_w(const float* __restrict__ Wq,
                                              const float* __restrict__ Wk,
                                              const float* __restrict__ Wv,
                                              unsigned short* __restrict__ WF) {
  int idx = (blockIdx.x * 256 + threadIdx.x) * 4;  // 192*1024 total
  int row = idx >> 10;
  int k   = idx & 1023;
  const float* src;
  float scale;
  if (row < 64)       { src = Wq + row * 1024 + k;         scale = 0.125f; }
  else if (row < 128) { src = Wk + (row - 64) * 1024 + k;  scale = 1.0f;   }
  else                { src = Wv + (row - 128) * 1024 + k; scale = 1.0f;   }
  float4 f = *(const float4*)src;
  ushort4 o;
  o.x = f2bf(f.x * scale); o.y = f2bf(f.y * scale);
  o.z = f2bf(f.z * scale); o.w = f2bf(f.w * scale);
  size_t off = ((size_t)(k >> 5) * 12 + (row >> 4)) * 512 +
               (((k >> 3) & 3) * 16 + (row & 15)) * 8 + (k & 7);
  *(ushort4*)(WF + off) = o;
}

// --- kernel 2: QKV projection, contiguous mega-DMA -------------------------
// 1024 blocks x 256 threads, 16 rows/block. LDS = row-major copy of the
// block's 64KB x-slab, with each 128B line's eight 16B units permuted by
// u -> (u&~7)|((u&7)^(row&7)) so A-frag ds_reads are 2 lanes/bank (free).
// Wave wv: stages DMA instrs [wv*16,wv*16+16); computes n-tiles wv*3..wv*3+2.
__global__ __launch_bounds__(256) void qkv(const float* __restrict__ x,
                                           const unsigned short* __restrict__ WF,
                                           unsigned short* __restrict__ Qg,
                                           unsigned short* __restrict__ KF,
                                           unsigned short* __restrict__ VF) {
  __shared__ alignas(16) char xs[65536];
  const int tid   = threadIdx.x;
  const int lane  = tid & 63;
  const int wv    = tid >> 6;        // 0..3
  const int quad  = lane >> 4;
  const int colid = lane & 15;
  const int row0  = blockIdx.x * 16;

  const char* xB = (const char*)x + (size_t)blockIdx.x * 65536;
  const unsigned short* wf = WF + lane * 8;

  // mega-stage: 64 x 1KB contiguous instrs (16 per wave)
  const int l8 = lane & ~7, l7 = lane & 7;
#pragma unroll
  for (int i = 0; i < 16; i++) {
    int j   = wv * 16 + i;           // instr j = slab bytes [j*1024, j*1024+1024)
    int key = (j >> 2) & 7;          // row of this 1KB = j>>2
    const char* src = xB + (size_t)j * 1024 + (l8 | (l7 ^ key)) * 16;
    dma16(src, &xs[j * 1024]);
  }
  __syncthreads();                   // single drain: whole slab resident

  v4f acc[3];
#pragma unroll
  for (int i = 0; i < 3; i++) acc[i] = (v4f){0.f, 0.f, 0.f, 0.f};

  const int c7 = colid & 7;
#pragma unroll 4
  for (int g = 0; g < 32; g++) {     // 32-K groups
    v8s bw[3];
#pragma unroll
    for (int ntl = 0; ntl < 3; ntl++)
      bw[ntl] = *(const v8s*)(wf + ((size_t)g * 12 + wv * 3 + ntl) * 512);
    int ug  = g * 8 + quad * 2;      // 16B-unit index within the row
    int su0 = (ug & ~7) | ((ug & 7) ^ c7);
    int su1 = (ug & ~7) | (((ug & 7) + 1) ^ c7);
    float4 f0 = *(const float4*)(&xs[colid * 4096 + su0 * 16]);
    float4 f1 = *(const float4*)(&xs[colid * 4096 + su1 * 16]);
    v8s a;
    a[0] = (short)f2bf(f0.x); a[1] = (short)f2bf(f0.y);
    a[2] = (short)f2bf(f0.z); a[3] = (short)f2bf(f0.w);
    a[4] = (short)f2bf(f1.x); a[5] = (short)f2bf(f1.y);
    a[6] = (short)f2bf(f1.z); a[7] = (short)f2bf(f1.w);
#pragma unroll
    for (int ntl = 0; ntl < 3; ntl++)
      acc[ntl] = __builtin_amdgcn_mfma_f32_16x16x32_bf16(a, bw[ntl], acc[ntl], 0, 0, 0);
  }

  // epilogue: wave wv stores n-tiles wv*3..wv*3+2
  const int trow_base = row0 + quad * 4;   // C/D row = quad*4+r, col = colid
#pragma unroll
  for (int ntl = 0; ntl < 3; ntl++) {
    const int nt = wv * 3 + ntl;
    if (nt < 4) {
#pragma unroll
      for (int r = 0; r < 4; r++)
        Qg[(size_t)(trow_base + r) * 64 + nt * 16 + colid] = f2bf(acc[ntl][r]);
    } else if (nt < 8) {
      int half = (nt - 4) >> 1;
      int q_f  = ((nt - 4) * 2 + (colid >> 3)) & 3;
      int j    = colid & 7;
#pragma unroll
      for (int r = 0; r < 4; r++) {
        int t  = trow_base + r;
        int b  = t >> 12, tl = t & 4095;
        int si = tl >> 6, sl = tl & 63;
        KF[((size_t)(b * 64 + si) * 8 + (sl >> 4) * 2 + half) * 512 +
           (q_f * 16 + (sl & 15)) * 8 + j] = f2bf(acc[ntl][r]);
      }
    } else {
#pragma unroll
      for (int r = 0; r < 4; r++) {
        int t  = trow_base + r;
        int b  = t >> 12, tl = t & 4095;
        int si = tl >> 6;
        int half = (tl >> 5) & 1, q_f = (tl >> 3) & 3, j = tl & 7;
        VF[((size_t)(b * 64 + si) * 8 + (nt - 8) * 2 + half) * 512 +
           (q_f * 16 + colid) * 8 + j] = f2bf(acc[ntl][r]);
      }
    }
  }
}

// --- kernel 3: causal flash (R13 verbatim) ----------------------------------
__global__ __launch_bounds__(256, 2) void flash(const unsigned short* __restrict__ Qg,
                                                const unsigned short* __restrict__ KF,
                                                const unsigned short* __restrict__ VF,
                                                float* __restrict__ out) {
  __shared__ alignas(16) char smem[4 * 32 * 68 * 4 + 4 * 32 * 4];
  unsigned short* pl = (unsigned short*)smem;
  float* redf = (float*)smem;
  float* lred = (float*)(smem + 4 * 32 * 68 * 4);

  const int tid   = threadIdx.x;
  const int lane  = tid & 63;
  const int wv    = tid >> 6;               // si-split id 0..3
  const int quad  = lane >> 4;
  const int colid = lane & 15;
  const int qt32  = 127 - (int)(blockIdx.x >> 2);   // longest-first
  const int b     = blockIdx.x & 3;
  const int bT    = b * 4096;
  const int row00 = qt32 * 32;
  const int qimax = (row00 + 31) >> 6;

  v8s qf[2][2];
#pragma unroll
  for (int mt = 0; mt < 2; mt++) {
    const unsigned short* qrow =
        Qg + (size_t)(bT + row00 + mt * 16 + colid) * 64 + quad * 8;
    qf[mt][0] = *(const v8s*)(qrow);
    qf[mt][1] = *(const v8s*)(qrow + 32);
  }

  v8s ones;
#pragma unroll
  for (int j = 0; j < 8; j++) ones[j] = (short)0x3F80;  // bf16 1.0

  v4f o[2][4];
#pragma unroll
  for (int mt = 0; mt < 2; mt++)
#pragma unroll
    for (int i = 0; i < 4; i++) o[mt][i] = (v4f){0.f, 0.f, 0.f, 0.f};
  v4f lac[2];
  lac[0] = (v4f){0.f, 0.f, 0.f, 0.f};
  lac[1] = (v4f){0.f, 0.f, 0.f, 0.f};

  const unsigned short* kb0 = KF + (size_t)b * 64 * 4096 + lane * 8;
  const unsigned short* vb0 = VF + (size_t)b * 64 * 4096 + lane * 8;

  for (int si = wv; si <= qimax; si += 4) {
    const unsigned short* ktile = kb0 + (size_t)si * 4096;
    const unsigned short* vtile = vb0 + (size_t)si * 4096;
    v8s ck[8], cv[8];
#pragma unroll
    for (int c = 0; c < 8; c++) ck[c] = *(const v8s*)(ktile + (size_t)c * 512);
#pragma unroll
    for (int c = 0; c < 8; c++) cv[c] = *(const v8s*)(vtile + (size_t)c * 512);

#pragma unroll
    for (int mt = 0; mt < 2; mt++) {
      v4f s[4];
#pragma unroll
      for (int i = 0; i < 4; i++) s[i] = (v4f){0.f, 0.f, 0.f, 0.f};
#pragma unroll
      for (int nt = 0; nt < 4; nt++) {
        s[nt] = __builtin_amdgcn_mfma_f32_16x16x32_bf16(qf[mt][0], ck[2 * nt], s[nt], 0, 0, 0);
        s[nt] = __builtin_amdgcn_mfma_f32_16x16x32_bf16(qf[mt][1], ck[2 * nt + 1], s[nt], 0, 0, 0);
      }

      if (si == qimax) {    // diagonal-containing tile: causal mask
        int rowb = row00 + mt * 16 + quad * 4;
        int colb = si * 64;
#pragma unroll
        for (int nt = 0; nt < 4; nt++)
#pragma unroll
          for (int r = 0; r < 4; r++)
            if (colb + nt * 16 + colid > rowb + r) s[nt][r] = -1e30f;
      }

      unsigned short* pw = pl + (wv * 2 + mt) * (16 * 72);
#pragma unroll
      for (int nt = 0; nt < 4; nt++)
#pragma unroll
        for (int r = 0; r < 4; r++)
          pw[(quad * 4 + r) * 72 + nt * 16 + colid] = f2bf(__expf(s[nt][r]));
    }

#pragma unroll
    for (int mt = 0; mt < 2; mt++) {
      unsigned short* pw = pl + (wv * 2 + mt) * (16 * 72);
#pragma unroll
      for (int ks = 0; ks < 64; ks += 32) {
        v8s af = *(const v8s*)(&pw[colid * 72 + ks + quad * 8]);
        lac[mt] = __builtin_amdgcn_mfma_f32_16x16x32_bf16(af, ones, lac[mt], 0, 0, 0);
#pragma unroll
        for (int nt = 0; nt < 4; nt++)
          o[mt][nt] = __builtin_amdgcn_mfma_f32_16x16x32_bf16(
              af, cv[2 * nt + (ks >> 5)], o[mt][nt], 0, 0, 0);
      }
    }
  }

  __syncthreads();
#pragma unroll
  for (int mt = 0; mt < 2; mt++) {
#pragma unroll
    for (int nt = 0; nt < 4; nt++)
#pragma unroll
      for (int r = 0; r < 4; r++)
        redf[(wv * 32 + mt * 16 + quad * 4 + r) * 68 + nt * 16 + colid] = o[mt][nt][r];
    if (colid == 0) {
#pragma unroll
      for (int r = 0; r < 4; r++)
        lred[wv * 32 + mt * 16 + quad * 4 + r] = lac[mt][r];
    }
  }
  __syncthreads();

  {
    int col = tid & 63;
    int r0  = tid >> 6;
#pragma unroll
    for (int rr = 0; rr < 8; rr++) {
      int row = r0 * 8 + rr;
      float sum = 0.f, lsum = 0.f;
#pragma unroll
      for (int w = 0; w < 4; w++) {
        sum  += redf[(w * 32 + row) * 68 + col];
        lsum += lred[w * 32 + row];
      }
      out[(size_t)(bT + row00 + row) * 64 + col] = sum / lsum;
    }
  }
}

extern "C" void kernel_launch(void* const* d_in, const int* in_sizes, int n_in,
                              void* d_out, int out_size, void* d_ws, size_t ws_size,
                              hipStream_t stream) {
  const float* x  = (const float*)d_in[0];
  const float* Wq = (const float*)d_in[1];
  const float* Wk = (const float*)d_in[2];
  const float* Wv = (const float*)d_in[3];
  float* out = (float*)d_out;

  unsigned short* WF = (unsigned short*)d_ws;          // 192*1024
  unsigned short* Qg = WF + 192 * 1024;                // 16384*64 row-major
  unsigned short* KF = Qg + 16384 * 64;                // fragment-linear
  unsigned short* VF = KF + 16384 * 64;                // fragment-linear

  hipLaunchKernelGGL(pack_w, dim3(192), dim3(256), 0, stream, Wq, Wk, Wv, WF);
  hipLaunchKernelGGL(qkv, dim3(1024), dim3(256), 0, stream, x, WF, Qg, KF, VF);
  hipLaunchKernelGGL(flash, dim3(512), dim3(256), 0, stream, Qg, KF, VF, out);
}